// Round 3
// baseline (7820.274 us; speedup 1.0000x reference)
//
#include <hip/hip_runtime.h>
#include <hip/hip_bf16.h>
#include <math.h>

#define HDIM 768
#define SEQ 512
#define BATCH 8
#define NHEAD 12
#define DHEAD 64
#define FFDIM 3072
#define NLAYER 12
#define NCLS 9

typedef _Float16 half8 __attribute__((ext_vector_type(8)));
typedef _Float16 half4v __attribute__((ext_vector_type(4)));
typedef float f32x4 __attribute__((ext_vector_type(4)));

// per-layer weight element counts/offsets in the transposed fp16 pool
#define OFF_QKV 0
#define OFF_AO  (768*2304)
#define OFF_FF1 (768*2304 + 768*768)
#define OFF_FF2 (768*2304 + 768*768 + 768*3072)
#define WELEMS  (768*2304 + 768*768 + 768*3072 + 3072*768)

// ---------------------------------------------------------------- block reduce
__device__ __forceinline__ float block_sum_256(float v, float* red) {
  #pragma unroll
  for (int o = 32; o > 0; o >>= 1) v += __shfl_down(v, o);
  int t = threadIdx.x;
  if ((t & 63) == 0) red[t >> 6] = v;
  __syncthreads();
  float r = red[0] + red[1] + red[2] + red[3];
  __syncthreads();
  return r;
}

// ---------------------------------------------------------------- embedding+LN
__global__ __launch_bounds__(256) void embed_ln_kernel(
    const int* __restrict__ ids, const float* __restrict__ tok,
    const float* __restrict__ pos, const float* __restrict__ typ,
    const float* __restrict__ gamma, const float* __restrict__ beta,
    float* __restrict__ xout)
{
  __shared__ float red[4];
  int row = blockIdx.x;
  int t = threadIdx.x;
  int s = row & (SEQ - 1);
  int id = ids[row];
  float v[3];
  #pragma unroll
  for (int k = 0; k < 3; k++) {
    int d = t + k * 256;
    v[k] = tok[(size_t)id * HDIM + d] + pos[(size_t)s * HDIM + d] + typ[d];
  }
  float total = block_sum_256(v[0] + v[1] + v[2], red);
  float mean = total * (1.0f / 768.0f);
  float sq = 0.0f;
  #pragma unroll
  for (int k = 0; k < 3; k++) { float d = v[k] - mean; sq += d * d; }
  float var = block_sum_256(sq, red) * (1.0f / 768.0f);
  float inv = rsqrtf(var + 1e-12f);
  #pragma unroll
  for (int k = 0; k < 3; k++) {
    int d = t + k * 256;
    xout[(size_t)row * HDIM + d] = (v[k] - mean) * inv * gamma[d] + beta[d];
  }
}

// ---------------------------------------------------------------- layernorm
__global__ __launch_bounds__(256) void ln_kernel(
    const float* __restrict__ in, const float* __restrict__ gamma,
    const float* __restrict__ beta, float* __restrict__ outp)
{
  __shared__ float red[4];
  int row = blockIdx.x, t = threadIdx.x;
  const float* ip = in + (size_t)row * HDIM;
  float v[3];
  #pragma unroll
  for (int k = 0; k < 3; k++) v[k] = ip[t + k * 256];
  float total = block_sum_256(v[0] + v[1] + v[2], red);
  float mean = total * (1.0f / 768.0f);
  float sq = 0.0f;
  #pragma unroll
  for (int k = 0; k < 3; k++) { float d = v[k] - mean; sq += d * d; }
  float var = block_sum_256(sq, red) * (1.0f / 768.0f);
  float inv = rsqrtf(var + 1e-12f);
  float* op = outp + (size_t)row * HDIM;
  #pragma unroll
  for (int k = 0; k < 3; k++) {
    int d = t + k * 256;
    op[d] = (v[k] - mean) * inv * gamma[d] + beta[d];
  }
}

// ---------------------------------------------------------------- W transpose+split
// W[K][N] fp32  ->  WT_hi/WT_lo [N][K] fp16 (hi = fp16(x), lo = fp16(x-hi))
__global__ __launch_bounds__(256) void convert_w_kernel(
    const float* __restrict__ w_qkv, const float* __restrict__ w_ao,
    const float* __restrict__ w_ff1, const float* __restrict__ w_ff2,
    _Float16* __restrict__ hi, _Float16* __restrict__ lo)
{
  int bid = blockIdx.x;
  const float* src; int K, N; size_t off; int tb;
  if (bid < 432)       { src = w_qkv; K = 768;  N = 2304; off = OFF_QKV; tb = bid; }
  else if (bid < 576)  { src = w_ao;  K = 768;  N = 768;  off = OFF_AO;  tb = bid - 432; }
  else if (bid < 1152) { src = w_ff1; K = 768;  N = 3072; off = OFF_FF1; tb = bid - 576; }
  else                 { src = w_ff2; K = 3072; N = 768;  off = OFF_FF2; tb = bid - 1152; }
  int ntn = N >> 6;
  int k0 = (tb / ntn) * 64, n0 = (tb % ntn) * 64;
  __shared__ float tile[64][65];
  int t = threadIdx.x;
  int r = t >> 4, c4 = (t & 15) * 4;
  #pragma unroll
  for (int i = 0; i < 4; i++) {
    float4 v = *(const float4*)(src + (size_t)(k0 + r + 16 * i) * N + n0 + c4);
    tile[r + 16 * i][c4 + 0] = v.x;
    tile[r + 16 * i][c4 + 1] = v.y;
    tile[r + 16 * i][c4 + 2] = v.z;
    tile[r + 16 * i][c4 + 3] = v.w;
  }
  __syncthreads();
  #pragma unroll
  for (int o = 0; o < 4; o++) {
    int n = r + 16 * o;
    half4v hv, lv;
    #pragma unroll
    for (int j = 0; j < 4; j++) {
      float x = tile[c4 + j][n];
      _Float16 h = (_Float16)x;
      hv[j] = h;
      lv[j] = (_Float16)(x - (float)h);
    }
    size_t idx = off + (size_t)(n0 + n) * K + k0 + c4;
    *(half4v*)&hi[idx] = hv;
    *(half4v*)&lo[idx] = lv;
  }
}

// ---------------------------------------------------------------- split-fp16 MFMA GEMM
// C[M,N] = A[M,K] @ W[K,N] (+bias)(+residual)(+gelu)
// A fp32 split on the fly; W pre-split as WT_hi/WT_lo [N][K] fp16.
// Tile BM x 128 x BK=32; 4 waves, wave-tile (BM/2) x 64; 3 MFMA per product.
__device__ __forceinline__ float gelu_exact(float x) {
  return 0.5f * x * (1.0f + erff(x * 0.70710678118654752440f));
}

template<int BM, bool GELU, bool RES>
__global__ __launch_bounds__(256) void gemm_mfma(
    const float* __restrict__ A, const _Float16* __restrict__ WTh,
    const _Float16* __restrict__ WTl, const float* __restrict__ bias,
    const float* __restrict__ Rsrc, float* __restrict__ C,
    int M, int N, int K)
{
  constexpr int MI = BM / 32;        // A-frags per wave (4 or 2)
  constexpr int TPR = 256 / BM;      // threads per A row
  constexpr int AW = BM / 8;         // A floats per thread (16 or 8)
  __shared__ _Float16 Ah[BM][40], Al[BM][40];
  __shared__ _Float16 Bh[128][40], Bl[128][40];

  int t = threadIdx.x;
  int n0 = blockIdx.x * 128, m0 = blockIdx.y * BM;
  int wave = t >> 6, lane = t & 63;
  int wm = (wave >> 1) * (BM / 2), wn = (wave & 1) * 64;
  int r15 = lane & 15, kg = lane >> 4;

  int ar = t / TPR, ac = (t % TPR) * AW;
  int br = t >> 1, bc = (t & 1) * 16;
  const float* Ap = A + (size_t)(m0 + ar) * K + ac;
  const _Float16* Bph = WTh + (size_t)(n0 + br) * K + bc;
  const _Float16* Bpl = WTl + (size_t)(n0 + br) * K + bc;

  f32x4 acc[MI][4];
  #pragma unroll
  for (int i = 0; i < MI; i++)
    #pragma unroll
    for (int j = 0; j < 4; j++) acc[i][j] = (f32x4){0.f, 0.f, 0.f, 0.f};

  for (int k0 = 0; k0 < K; k0 += 32) {
    // global loads
    float af[AW];
    #pragma unroll
    for (int c = 0; c < AW / 4; c++) {
      float4 v = *(const float4*)(Ap + k0 + c * 4);
      af[c * 4 + 0] = v.x; af[c * 4 + 1] = v.y;
      af[c * 4 + 2] = v.z; af[c * 4 + 3] = v.w;
    }
    float4 bh0 = *(const float4*)(Bph + k0);
    float4 bh1 = *(const float4*)(Bph + k0 + 8);
    float4 bl0 = *(const float4*)(Bpl + k0);
    float4 bl1 = *(const float4*)(Bpl + k0 + 8);

    __syncthreads();   // previous iteration's reads done
    #pragma unroll
    for (int c = 0; c < AW / 8; c++) {
      half8 hv, lv;
      #pragma unroll
      for (int e = 0; e < 8; e++) {
        float x = af[c * 8 + e];
        _Float16 h = (_Float16)x;
        hv[e] = h;
        lv[e] = (_Float16)(x - (float)h);
      }
      *(half8*)&Ah[ar][ac + c * 8] = hv;
      *(half8*)&Al[ar][ac + c * 8] = lv;
    }
    *(float4*)&Bh[br][bc]     = bh0;
    *(float4*)&Bh[br][bc + 8] = bh1;
    *(float4*)&Bl[br][bc]     = bl0;
    *(float4*)&Bl[br][bc + 8] = bl1;
    __syncthreads();

    // fragments + MFMA
    half8 ahf[MI], alf[MI];
    #pragma unroll
    for (int i = 0; i < MI; i++) {
      ahf[i] = *(const half8*)&Ah[wm + i * 16 + r15][kg * 8];
      alf[i] = *(const half8*)&Al[wm + i * 16 + r15][kg * 8];
    }
    #pragma unroll
    for (int j = 0; j < 4; j++) {
      half8 bhf = *(const half8*)&Bh[wn + j * 16 + r15][kg * 8];
      half8 blf = *(const half8*)&Bl[wn + j * 16 + r15][kg * 8];
      #pragma unroll
      for (int i = 0; i < MI; i++) {
        acc[i][j] = __builtin_amdgcn_mfma_f32_16x16x32_f16(ahf[i], bhf, acc[i][j], 0, 0, 0);
        acc[i][j] = __builtin_amdgcn_mfma_f32_16x16x32_f16(ahf[i], blf, acc[i][j], 0, 0, 0);
        acc[i][j] = __builtin_amdgcn_mfma_f32_16x16x32_f16(alf[i], bhf, acc[i][j], 0, 0, 0);
      }
    }
  }

  // epilogue: D row=(lane>>4)*4+reg, col=lane&15  [verified m89/m91]
  #pragma unroll
  for (int i = 0; i < MI; i++)
    #pragma unroll
    for (int j = 0; j < 4; j++)
      #pragma unroll
      for (int q = 0; q < 4; q++) {
        int row = m0 + wm + i * 16 + kg * 4 + q;
        int col = n0 + wn + j * 16 + r15;
        float v = acc[i][j][q] + bias[col];
        if (RES) v += Rsrc[(size_t)row * N + col];
        if (GELU) v = gelu_exact(v);
        C[(size_t)row * N + col] = v;
      }
}

// ---------------------------------------------------------------- attention
__device__ __forceinline__ int swz(int jl, int d) {
  return jl * 64 + ((((d) >> 3) ^ (jl & 7)) << 3) + ((d) & 7);
}

__global__ __launch_bounds__(256) void attn_kernel(
    const float* __restrict__ qkv, const int* __restrict__ maskp,
    float* __restrict__ ctxo)
{
  __shared__ float ss[16][516];
  __shared__ float qs[16][68];
  __shared__ float ks[64 * 64];

  int t = threadIdx.x;
  int qt = blockIdx.x, bh = blockIdx.y;
  int b = bh / NHEAD, h = bh % NHEAD;
  int q0 = qt * 16;
  const float* Qb = qkv + (size_t)b * SEQ * 2304 + h * 64;
  const float* Kb = Qb + 768;
  const float* Vb = Qb + 1536;

  {
    int r = t >> 4, d0 = (t & 15) * 4;
    *(float4*)&qs[r][d0] = *(const float4*)(Qb + (size_t)(q0 + r) * 2304 + d0);
  }
  __syncthreads();

  int r = t >> 4, j16 = t & 15;

  for (int jt = 0; jt < 8; jt++) {
    int kr = t >> 2, kc0 = (t & 3) * 16;
    const float* src = Kb + (size_t)(jt * 64 + kr) * 2304 + kc0;
    float4 kv0 = *(const float4*)(src + 0);
    float4 kv1 = *(const float4*)(src + 4);
    float4 kv2 = *(const float4*)(src + 8);
    float4 kv3 = *(const float4*)(src + 12);
    __syncthreads();
    *(float4*)&ks[swz(kr, kc0 + 0)]  = kv0;
    *(float4*)&ks[swz(kr, kc0 + 4)]  = kv1;
    *(float4*)&ks[swz(kr, kc0 + 8)]  = kv2;
    *(float4*)&ks[swz(kr, kc0 + 12)] = kv3;
    __syncthreads();
    float sacc[4] = {0, 0, 0, 0};
    #pragma unroll
    for (int d0 = 0; d0 < 64; d0 += 4) {
      float4 qv = *(const float4*)&qs[r][d0];
      #pragma unroll
      for (int jj = 0; jj < 4; jj++) {
        int jl = jj * 16 + j16;
        float4 kv = *(const float4*)&ks[swz(jl, d0)];
        sacc[jj] += qv.x * kv.x + qv.y * kv.y + qv.z * kv.z + qv.w * kv.w;
      }
    }
    #pragma unroll
    for (int jj = 0; jj < 4; jj++) {
      int j = jt * 64 + jj * 16 + j16;
      float mb = (1.0f - (float)maskp[b * SEQ + j]) * -10000.0f;
      ss[r][j] = sacc[jj] * 0.125f + mb;
    }
    __syncthreads();
  }

  {
    float mx = -1e30f;
    for (int j = j16; j < 512; j += 16) mx = fmaxf(mx, ss[r][j]);
    #pragma unroll
    for (int o = 1; o < 16; o <<= 1) mx = fmaxf(mx, __shfl_xor(mx, o));
    float l = 0.0f;
    for (int j = j16; j < 512; j += 16) {
      float p = expf(ss[r][j] - mx);
      ss[r][j] = p;
      l += p;
    }
    #pragma unroll
    for (int o = 1; o < 16; o <<= 1) l += __shfl_xor(l, o);
    float inv = 1.0f / l;
    for (int j = j16; j < 512; j += 16) ss[r][j] *= inv;
  }
  __syncthreads();

  int dl = t & 15;
  float acc[4] = {0, 0, 0, 0};
  for (int jt = 0; jt < 8; jt++) {
    int kr = t >> 2, kc0 = (t & 3) * 16;
    const float* src = Vb + (size_t)(jt * 64 + kr) * 2304 + kc0;
    float4 kv0 = *(const float4*)(src + 0);
    float4 kv1 = *(const float4*)(src + 4);
    float4 kv2 = *(const float4*)(src + 8);
    float4 kv3 = *(const float4*)(src + 12);
    __syncthreads();
    *(float4*)&ks[swz(kr, kc0 + 0)]  = kv0;
    *(float4*)&ks[swz(kr, kc0 + 4)]  = kv1;
    *(float4*)&ks[swz(kr, kc0 + 8)]  = kv2;
    *(float4*)&ks[swz(kr, kc0 + 12)] = kv3;
    __syncthreads();
    #pragma unroll
    for (int jl4 = 0; jl4 < 16; jl4++) {
      float4 pv = *(const float4*)&ss[r][jt * 64 + jl4 * 4];
      float pl[4] = {pv.x, pv.y, pv.z, pv.w};
      #pragma unroll
      for (int q = 0; q < 4; q++) {
        int jl = jl4 * 4 + q;
        float4 kv = *(const float4*)&ks[swz(jl, dl * 4)];
        acc[0] += pl[q] * kv.x;
        acc[1] += pl[q] * kv.y;
        acc[2] += pl[q] * kv.z;
        acc[3] += pl[q] * kv.w;
      }
    }
    __syncthreads();
  }
  float4 outv = {acc[0], acc[1], acc[2], acc[3]};
  *(float4*)(ctxo + (size_t)(b * SEQ + q0 + r) * HDIM + h * 64 + dl * 4) = outv;
}

// ---------------------------------------------------------------- head (768->9)
__global__ __launch_bounds__(256) void head_kernel(
    const float* __restrict__ x, const float* __restrict__ W,
    const float* __restrict__ bias, float* __restrict__ em)
{
  int wid = threadIdx.x >> 6, lane = threadIdx.x & 63;
  int row = blockIdx.x * 4 + wid;
  const float* xp = x + (size_t)row * HDIM;
  float xv[12];
  #pragma unroll
  for (int k = 0; k < 12; k++) xv[k] = xp[lane + k * 64];
  for (int c = 0; c < NCLS; c++) {
    float p = 0.0f;
    #pragma unroll
    for (int k = 0; k < 12; k++) p += xv[k] * W[(lane + k * 64) * NCLS + c];
    #pragma unroll
    for (int o = 32; o > 0; o >>= 1) p += __shfl_down(p, o);
    if (lane == 0) em[(size_t)row * NCLS + c] = p + bias[c];
  }
}

// ---------------------------------------------------------------- CRF -llh
__global__ __launch_bounds__(512) void crf_kernel(
    const float* __restrict__ em, const int* __restrict__ labels,
    const int* __restrict__ maskp, const float* __restrict__ trans,
    const float* __restrict__ start_t, const float* __restrict__ end_t,
    float* __restrict__ out)
{
  __shared__ float tr_s[81];
  __shared__ float res[8];
  int t = threadIdx.x;
  if (t < 81) tr_s[t] = trans[t];
  __syncthreads();
  int b = t >> 6, lane = t & 63;
  int j = (lane < NCLS) ? lane : 0;

  float alpha = start_t[j] + em[(size_t)(b * SEQ) * NCLS + j];
  for (int step = 1; step < SEQ; step++) {
    int m = maskp[b * SEQ + step];
    float c[9], mx = -1e30f;
    #pragma unroll
    for (int i = 0; i < 9; i++) {
      float ai = __shfl(alpha, i);
      float v = ai + tr_s[i * 9 + j];
      c[i] = v;
      mx = fmaxf(mx, v);
    }
    float s = 0.0f;
    #pragma unroll
    for (int i = 0; i < 9; i++) s += expf(c[i] - mx);
    float nxt = mx + logf(s) + em[(size_t)(b * SEQ + step) * NCLS + j];
    if (m && lane < NCLS) alpha = nxt;
  }
  float val = (lane < NCLS) ? alpha + end_t[lane] : -1e30f;
  float mx = -1e30f;
  #pragma unroll
  for (int i = 0; i < 9; i++) mx = fmaxf(mx, __shfl(val, i));
  float sm = 0.0f;
  #pragma unroll
  for (int i = 0; i < 9; i++) sm += expf(__shfl(val, i) - mx);
  float logZ = mx + logf(sm);

  float part = 0.0f;
  int cnt = 0;
  for (int step = lane; step < SEQ; step += 64) cnt += maskp[b * SEQ + step];
  for (int step = 1 + lane; step < SEQ; step += 64) {
    if (maskp[b * SEQ + step]) {
      int tp = labels[b * SEQ + step - 1];
      int tc = labels[b * SEQ + step];
      part += tr_s[tp * 9 + tc] + em[(size_t)(b * SEQ + step) * NCLS + tc];
    }
  }
  #pragma unroll
  for (int o = 32; o > 0; o >>= 1) {
    part += __shfl_down(part, o);
    cnt  += __shfl_down(cnt, o);
  }
  if (lane == 0) {
    int t0 = labels[b * SEQ];
    float num = part + start_t[t0] + em[(size_t)(b * SEQ) * NCLS + t0];
    int last = cnt - 1;
    int tl = labels[b * SEQ + last];
    num += end_t[tl];
    res[b] = num - logZ;
  }
  __syncthreads();
  if (t == 0) {
    float s = 0.0f;
    #pragma unroll
    for (int bb = 0; bb < 8; bb++) s += res[bb];
    out[0] = -s;
  }
}

// ---------------------------------------------------------------- Viterbi
__global__ __launch_bounds__(512) void viterbi_kernel(
    const float* __restrict__ em, const int* __restrict__ maskp,
    const float* __restrict__ trans, const float* __restrict__ start_t,
    const float* __restrict__ end_t, float* __restrict__ tags_out)
{
  __shared__ float tr_s[81];
  __shared__ unsigned char hist[BATCH][SEQ - 1][NCLS];
  int t = threadIdx.x;
  if (t < 81) tr_s[t] = trans[t];
  __syncthreads();
  int b = t >> 6, lane = t & 63;
  int j = (lane < NCLS) ? lane : 0;

  float score = start_t[j] + em[(size_t)(b * SEQ) * NCLS + j];
  for (int step = 1; step < SEQ; step++) {
    float best = -1e30f;
    int bi = 0;
    #pragma unroll
    for (int i = 0; i < 9; i++) {
      float v = __shfl(score, i) + tr_s[i * 9 + j];
      if (v > best) { best = v; bi = i; }
    }
    int m = maskp[b * SEQ + step];
    float e = em[(size_t)(b * SEQ + step) * NCLS + j];
    if (lane < NCLS) hist[b][step - 1][j] = (unsigned char)bi;
    if (m && lane < NCLS) score = best + e;
  }
  __syncthreads();

  float val = (lane < NCLS) ? score + end_t[lane] : -1e30f;
  int last = 0;
  float bb = -1e30f;
  #pragma unroll
  for (int i = 0; i < 9; i++) {
    float v = __shfl(val, i);
    if (v > bb) { bb = v; last = i; }
  }
  if (lane == 0) {
    int tag = last;
    for (int k = SEQ - 2; k >= 0; k--) {
      tags_out[b * SEQ + k + 1] = (float)tag;
      if (maskp[b * SEQ + k + 1]) tag = hist[b][k][tag];
    }
    tags_out[b * SEQ] = (float)tag;
  }
}

// ---------------------------------------------------------------- launch
extern "C" void kernel_launch(void* const* d_in, const int* in_sizes, int n_in,
                              void* d_out, int out_size, void* d_ws, size_t ws_size,
                              hipStream_t stream) {
  const int*   input_ids      = (const int*)d_in[0];
  const int*   attention_mask = (const int*)d_in[1];
  const int*   labels         = (const int*)d_in[2];
  const float* tok_emb  = (const float*)d_in[3];
  const float* pos_emb  = (const float*)d_in[4];
  const float* type_emb = (const float*)d_in[5];
  const float* emb_ln_s = (const float*)d_in[6];
  const float* emb_ln_b = (const float*)d_in[7];
  const float* qkv_w    = (const float*)d_in[8];
  const float* qkv_b    = (const float*)d_in[9];
  const float* ao_w     = (const float*)d_in[10];
  const float* ao_b     = (const float*)d_in[11];
  const float* ln1_s    = (const float*)d_in[12];
  const float* ln1_b    = (const float*)d_in[13];
  const float* ff1_w    = (const float*)d_in[14];
  const float* ff1_b    = (const float*)d_in[15];
  const float* ff2_w    = (const float*)d_in[16];
  const float* ff2_b    = (const float*)d_in[17];
  const float* ln2_s    = (const float*)d_in[18];
  const float* ln2_b    = (const float*)d_in[19];
  const float* head_w   = (const float*)d_in[20];
  const float* head_b   = (const float*)d_in[21];
  const float* trans    = (const float*)d_in[22];
  const float* start_t  = (const float*)d_in[23];
  const float* end_t    = (const float*)d_in[24];

  const size_t ROWS = (size_t)BATCH * SEQ;   // 4096
  float* ws   = (float*)d_ws;
  float* x    = ws;                               // 4096*768
  float* qkvb = x + ROWS * HDIM;                  // 4096*2304
  float* ctxb = qkvb + ROWS * 2304;               // 4096*768
  float* hmid = qkvb;                             // aliases qkv+ctx buffers
  float* tmp  = ctxb + ROWS * HDIM;               // 4096*768
  float* em   = tmp + ROWS * HDIM;                // 4096*9
  _Float16* wt_hi = (_Float16*)(em + ROWS * NCLS + 64);  // WELEMS fp16
  _Float16* wt_lo = wt_hi + WELEMS;                      // WELEMS fp16

  embed_ln_kernel<<<ROWS, 256, 0, stream>>>(input_ids, tok_emb, pos_emb,
                                            type_emb, emb_ln_s, emb_ln_b, x);

  for (int i = 0; i < NLAYER; i++) {
    convert_w_kernel<<<1728, 256, 0, stream>>>(
        qkv_w + (size_t)i * HDIM * 2304, ao_w + (size_t)i * HDIM * HDIM,
        ff1_w + (size_t)i * HDIM * FFDIM, ff2_w + (size_t)i * FFDIM * HDIM,
        wt_hi, wt_lo);
    gemm_mfma<128, false, false><<<dim3(18, 32), 256, 0, stream>>>(
        x, wt_hi + OFF_QKV, wt_lo + OFF_QKV, qkv_b + (size_t)i * 2304,
        nullptr, qkvb, 4096, 2304, 768);
    attn_kernel<<<dim3(32, 96), 256, 0, stream>>>(qkvb, attention_mask, ctxb);
    gemm_mfma<64, false, true><<<dim3(6, 64), 256, 0, stream>>>(
        ctxb, wt_hi + OFF_AO, wt_lo + OFF_AO, ao_b + (size_t)i * HDIM,
        x, tmp, 4096, 768, 768);
    ln_kernel<<<ROWS, 256, 0, stream>>>(tmp, ln1_s + (size_t)i * HDIM,
                                        ln1_b + (size_t)i * HDIM, x);
    gemm_mfma<128, true, false><<<dim3(24, 32), 256, 0, stream>>>(
        x, wt_hi + OFF_FF1, wt_lo + OFF_FF1, ff1_b + (size_t)i * FFDIM,
        nullptr, hmid, 4096, 3072, 768);
    gemm_mfma<64, false, true><<<dim3(6, 64), 256, 0, stream>>>(
        hmid, wt_hi + OFF_FF2, wt_lo + OFF_FF2, ff2_b + (size_t)i * HDIM,
        x, tmp, 4096, 768, 3072);
    ln_kernel<<<ROWS, 256, 0, stream>>>(tmp, ln2_s + (size_t)i * HDIM,
                                        ln2_b + (size_t)i * HDIM, x);
  }

  head_kernel<<<1024, 256, 0, stream>>>(x, head_w, head_b, em);
  crf_kernel<<<1, 512, 0, stream>>>(em, labels, attention_mask, trans,
                                    start_t, end_t, (float*)d_out);
  viterbi_kernel<<<1, 512, 0, stream>>>(em, attention_mask, trans, start_t,
                                        end_t, (float*)d_out + 1);
}